// Round 2
// baseline (1622.770 us; speedup 1.0000x reference)
//
#include <hip/hip_runtime.h>

#define NB 32
#define TT 2048
#define II 256
#define HH 512
#define LCH 16
#define NCH 128

typedef short s8v __attribute__((ext_vector_type(8)));
typedef __bf16 bf8v __attribute__((ext_vector_type(8)));
typedef float f4v __attribute__((ext_vector_type(4)));

#define DEVI static __device__ __forceinline__

DEVI float bf2f(short s){ union{unsigned u; float f;} c; c.u = ((unsigned)(unsigned short)s) << 16; return c.f; }
DEVI short f2bf(float f){ union{float f; unsigned u;} c; c.f = f; unsigned u = c.u; u += 0x7FFF + ((u >> 16) & 1); return (short)(u >> 16); }
DEVI f4v fzero(){ f4v z = {0.0f,0.0f,0.0f,0.0f}; return z; }

DEVI f4v mfma16(s8v a, s8v b, f4v c){
  union{ s8v s; bf8v b; } ua, ub; ua.s = a; ub.s = b;
  return __builtin_amdgcn_mfma_f32_16x16x32_bf16(ua.b, ub.b, c, 0, 0, 0);
}

// A-frag / B^T-frag: lane holds M[row0 + (lane&15)][k0 + (lane>>4)*8 + 0..7]
DEVI s8v ldfrag_bf(const short* base, int row0, int ld, int k0, int lane){
  const short* p = base + (size_t)(row0 + (lane & 15)) * ld + k0 + ((lane >> 4) << 3);
  return *(const s8v*)p;
}
DEVI s8v ldfrag_f32(const float* base, int row0, int ld, int k0, int lane){
  const float* p = base + (size_t)(row0 + (lane & 15)) * ld + k0 + ((lane >> 4) << 3);
  f4v lo = *(const f4v*)p;
  f4v hi = *(const f4v*)(p + 4);
  s8v o;
  o[0]=f2bf(lo[0]); o[1]=f2bf(lo[1]); o[2]=f2bf(lo[2]); o[3]=f2bf(lo[3]);
  o[4]=f2bf(hi[0]); o[5]=f2bf(hi[1]); o[6]=f2bf(hi[2]); o[7]=f2bf(hi[3]);
  return o;
}

// XOR swizzle for LDS state buffers (row stride 512 bf16 = 1024 B)
DEVI int swzoff(int row, int col){ return (row << 9) + ((((col >> 3) ^ (row & 7)) << 3) | (col & 7)); }

// ---------------- fp32 W_hh -> bf16 mats[0] + transpose matsT[0] ----------------
__global__ __launch_bounds__(256) void k_init_p1(const float* __restrict__ W,
                                                 short* __restrict__ mats, short* __restrict__ matsT){
  __shared__ short tile[64][65];
  int bx = blockIdx.x, by = blockIdx.y;
  int t = threadIdx.x;
  for(int i = 0; i < 16; ++i){
    int idx = t + 256*i;
    int rr = idx >> 6, cc = idx & 63;
    short v = f2bf(W[(size_t)(64*by + rr)*HH + 64*bx + cc]);
    tile[rr][cc] = v;
    mats[(size_t)(64*by + rr)*HH + 64*bx + cc] = v;
  }
  __syncthreads();
  for(int i = 0; i < 16; ++i){
    int idx = t + 256*i;
    int rr = idx >> 6, cc = idx & 63;
    matsT[(size_t)(64*bx + rr)*HH + 64*by + cc] = tile[cc][rr];
  }
}

// ---------------- fp32 -> bf16 elementwise (for W_ih) ----------------
__global__ __launch_bounds__(256) void k_cvt(const float* __restrict__ src, short* __restrict__ dst, int n){
  for(int i = blockIdx.x*256 + threadIdx.x; i < n; i += gridDim.x*256) dst[i] = f2bf(src[i]);
}

// ---------------- batched bf16 512x512 product C = A*B (Bt given), writes C and C^T ----------------
struct ProdArgs {
  const short* A[8]; const short* Bt[8]; short* C[8]; short* Ct[8];
};
__global__ __launch_bounds__(256) void k_prod(ProdArgs args){
  int bz = blockIdx.z;
  const short* A  = args.A[bz];
  const short* Bt = args.Bt[bz];
  short* C  = args.C[bz];
  short* Ct = args.Ct[bz];
  int wave = threadIdx.x >> 6, lane = threadIdx.x & 63;
  int mrow0 = blockIdx.x*64 + (wave & 1)*32;
  int ncol0 = blockIdx.y*128 + (wave >> 1)*64;
  f4v acc[2][4];
  for(int mi=0;mi<2;mi++) for(int j=0;j<4;j++) acc[mi][j] = fzero();
  for(int k0 = 0; k0 < HH; k0 += 32){
    s8v a0 = ldfrag_bf(A, mrow0,      HH, k0, lane);
    s8v a1 = ldfrag_bf(A, mrow0 + 16, HH, k0, lane);
    #pragma unroll
    for(int j = 0; j < 4; ++j){
      s8v b = ldfrag_bf(Bt, ncol0 + (j<<4), HH, k0, lane);
      acc[0][j] = mfma16(a0, b, acc[0][j]);
      acc[1][j] = mfma16(a1, b, acc[1][j]);
    }
  }
  int q = lane >> 4, c0 = lane & 15;
  for(int mi=0;mi<2;mi++) for(int j=0;j<4;j++) for(int r=0;r<4;r++){
    int row = mrow0 + (mi<<4) + (q<<2) + r;
    int col = ncol0 + (j<<4) + c0;
    short v = f2bf(acc[mi][j][r]);
    C [(size_t)row*HH + col] = v;
    Ct[(size_t)col*HH + row] = v;
  }
}

// ---------------- proj = x @ W_ih^T + b_ih (bf16 out); hid0 = initial + proj[:,0] (fp32 -> Y0[0]) ----------------
__global__ __launch_bounds__(256) void k_proj(const float* __restrict__ x, const short* __restrict__ Wihb,
                                              const float* __restrict__ bih, const float* __restrict__ initial,
                                              short* __restrict__ projb, float* __restrict__ Y00){
  int wave = threadIdx.x >> 6, lane = threadIdx.x & 63;
  int mrow0 = blockIdx.x*64 + (wave & 1)*32;          // row m = n*2048 + t
  int ncol0 = blockIdx.y*128 + (wave >> 1)*64;
  f4v acc[2][4];
  for(int mi=0;mi<2;mi++) for(int j=0;j<4;j++) acc[mi][j] = fzero();
  for(int k0 = 0; k0 < II; k0 += 32){
    s8v a0 = ldfrag_f32(x, mrow0,      II, k0, lane);
    s8v a1 = ldfrag_f32(x, mrow0 + 16, II, k0, lane);
    #pragma unroll
    for(int j = 0; j < 4; ++j){
      s8v b = ldfrag_bf(Wihb, ncol0 + (j<<4), II, k0, lane);
      acc[0][j] = mfma16(a0, b, acc[0][j]);
      acc[1][j] = mfma16(a1, b, acc[1][j]);
    }
  }
  int q = lane >> 4, c0 = lane & 15;
  for(int mi=0;mi<2;mi++) for(int j=0;j<4;j++) for(int r=0;r<4;r++){
    int row = mrow0 + (mi<<4) + (q<<2) + r;
    int col = ncol0 + (j<<4) + c0;
    float v = acc[mi][j][r] + bih[col];
    projb[(size_t)row*HH + col] = f2bf(v);
    if((row & (TT-1)) == 0){
      int n = row >> 11;
      Y00[(size_t)n*HH + col] = v + initial[(size_t)n*HH + col];
    }
  }
}

// ---------------- per-chunk local scan (serial L steps) ----------------
// bf16 state in LDS (swizzled, double-buffered); fp32 s_t -> sout; fp32 chunk-final -> Y0[c+1].
__global__ __launch_bounds__(512) void k_scan(const short* __restrict__ projb,
                                              const short* __restrict__ Whhb,
                                              float* __restrict__ sout, float* __restrict__ Y0){
  __shared__ short st[2][NB*HH];
  int c = blockIdx.x;
  int tid = threadIdx.x;
  int wave = tid >> 6, lane = tid & 63;
  int q = lane >> 4, c0 = lane & 15;
  int ncol0 = wave << 6;                 // 8 waves x 64 cols
  for(int i = tid; i < NB*HH; i += 512) st[0][i] = 0;
  __syncthreads();
  int cur = 0;
  int tmax = min(LCH, 2047 - LCH*c);
  for(int tl = 1; tl <= tmax; ++tl){
    int t = LCH*c + tl;
    int nxt = cur ^ 1;
    // stage proj[:, t-1, wave's 64 cols) into st[nxt]
    for(int i = 0; i < 16; ++i){
      int pidx = lane + (i << 6);        // 0..1023 int-pairs
      int rown = pidx >> 5;              // 0..31
      int col  = ncol0 + ((pidx & 31) << 1);
      int v = *(const int*)(projb + ((size_t)rown*TT + (t-1))*HH + col);
      *(int*)(st[nxt] + swzoff(rown, col)) = v;
    }
    // acc = s_prev @ Whh^T (this wave's 64 output cols)
    f4v acc[2][4];
    for(int mi=0;mi<2;mi++) for(int j=0;j<4;j++) acc[mi][j] = fzero();
    for(int k0 = 0; k0 < HH; k0 += 32){
      int colb = k0 + (q << 3);
      s8v a0 = *(const s8v*)(st[cur] + swzoff(c0,      colb));
      s8v a1 = *(const s8v*)(st[cur] + swzoff(c0 + 16, colb));
      #pragma unroll
      for(int j = 0; j < 4; ++j){
        s8v b = ldfrag_bf(Whhb, ncol0 + (j<<4), HH, k0, lane);
        acc[0][j] = mfma16(a0, b, acc[0][j]);
        acc[1][j] = mfma16(a1, b, acc[1][j]);
      }
    }
    // s_new (fp32) = acc + p; LDS gets bf16; global gets fp32; boundary fp32
    #pragma unroll
    for(int mi=0;mi<2;mi++)
    #pragma unroll
    for(int j=0;j<4;j++)
    #pragma unroll
    for(int r=0;r<4;r++){
      int rown = (mi<<4) + (q<<2) + r;
      int col  = ncol0 + (j<<4) + c0;
      int so = swzoff(rown, col);
      float sv = acc[mi][j][r] + bf2f(st[nxt][so]);
      st[nxt][so] = f2bf(sv);
      sout[((size_t)rown*TT + t)*HH + col] = sv;
      if(tl == LCH) Y0[(((size_t)(c+1))*NB + rown)*HH + col] = sv;
    }
    __syncthreads();
    cur = nxt;
  }
}

// ---------------- Kogge-Stone level: Yout[i] = Yin[i] + Yin[i-s] @ As^T ----------------
__global__ __launch_bounds__(256) void k_ks(const float* __restrict__ Yin, float* __restrict__ Yout,
                                            const short* __restrict__ As, int s){
  int i = blockIdx.x;
  if(i < s){
    const float* src = Yin + (size_t)i*NB*HH;
    float* dst = Yout + (size_t)i*NB*HH;
    for(int idx = threadIdx.x; idx < NB*HH; idx += 256) dst[idx] = src[idx];
    return;
  }
  const float* Xp = Yin + (size_t)(i - s)*NB*HH;
  const float* Xc = Yin + (size_t)i*NB*HH;
  float* Out = Yout + (size_t)i*NB*HH;
  int wave = threadIdx.x >> 6, lane = threadIdx.x & 63;
  int ncol0 = wave << 7;                  // 4 waves x 128 cols
  f4v acc[2][8];
  for(int mi=0;mi<2;mi++) for(int j=0;j<8;j++) acc[mi][j] = fzero();
  for(int k0 = 0; k0 < HH; k0 += 32){
    s8v a0 = ldfrag_f32(Xp, 0,  HH, k0, lane);
    s8v a1 = ldfrag_f32(Xp, 16, HH, k0, lane);
    #pragma unroll
    for(int j = 0; j < 8; ++j){
      s8v b = ldfrag_bf(As, ncol0 + (j<<4), HH, k0, lane);
      acc[0][j] = mfma16(a0, b, acc[0][j]);
      acc[1][j] = mfma16(a1, b, acc[1][j]);
    }
  }
  int q = lane >> 4, c0 = lane & 15;
  for(int mi=0;mi<2;mi++) for(int j=0;j<8;j++) for(int r=0;r<4;r++){
    int rown = (mi<<4) + (q<<2) + r;
    int col  = ncol0 + (j<<4) + c0;
    Out[(size_t)rown*HH + col] = acc[mi][j][r] + Xc[(size_t)rown*HH + col];
  }
}

// ---------------- fix-up: hid_t = s_t + H_c @ (W^k)^T ; writes both fp32 output copies ----------------
__global__ __launch_bounds__(256) void k_fix(const float* __restrict__ SS, const short* __restrict__ mats,
                                             float* io1, float* __restrict__ out2){
  int bz = blockIdx.z;
  if(bz == LCH){                          // t = 0 slice
    if(blockIdx.x == 0 && blockIdx.y == 0){
      for(int idx = threadIdx.x; idx < NB*HH; idx += 256){
        int n = idx >> 9, h = idx & (HH-1);
        float v = SS[idx];                // SS rows 0..31 = H_0 = hid_0
        size_t o = ((size_t)n*TT + 0)*HH + h;
        io1[o] = v; out2[o] = v;
      }
    }
    return;
  }
  int k = bz + 1;                         // 1..16
  const short* P = mats + (size_t)(k-1)*HH*HH;
  int wave = threadIdx.x >> 6, lane = threadIdx.x & 63;
  int mrow0 = blockIdx.x*64 + (wave & 1)*32;     // row in SS [4096 x 512]
  int ncol0 = blockIdx.y*128 + (wave >> 1)*64;
  f4v acc[2][4];
  for(int mi=0;mi<2;mi++) for(int j=0;j<4;j++) acc[mi][j] = fzero();
  for(int k0 = 0; k0 < HH; k0 += 32){
    s8v a0 = ldfrag_f32(SS, mrow0,      HH, k0, lane);
    s8v a1 = ldfrag_f32(SS, mrow0 + 16, HH, k0, lane);
    #pragma unroll
    for(int j = 0; j < 4; ++j){
      s8v b = ldfrag_bf(P, ncol0 + (j<<4), HH, k0, lane);
      acc[0][j] = mfma16(a0, b, acc[0][j]);
      acc[1][j] = mfma16(a1, b, acc[1][j]);
    }
  }
  int q = lane >> 4, c0 = lane & 15;
  for(int mi=0;mi<2;mi++) for(int j=0;j<4;j++) for(int r=0;r<4;r++){
    int row = mrow0 + (mi<<4) + (q<<2) + r;
    int col = ncol0 + (j<<4) + c0;
    int c = row >> 5, n = row & (NB-1);
    int t = LCH*c + k;
    if(t < TT){
      size_t o = ((size_t)n*TT + t)*HH + col;
      float v = acc[mi][j][r] + io1[o];   // io1 holds fp32 s_t
      io1[o] = v; out2[o] = v;
    }
  }
}

extern "C" void kernel_launch(void* const* d_in, const int* in_sizes, int n_in,
                              void* d_out, int out_size, void* d_ws, size_t ws_size,
                              hipStream_t stream) {
  const float* x       = (const float*)d_in[0];  // [32,2048,256] fp32
  const float* initial = (const float*)d_in[1];  // [32,512]
  const float* Wih     = (const float*)d_in[2];  // [512,256]
  const float* bih     = (const float*)d_in[3];  // [512]
  const float* Whh     = (const float*)d_in[4];  // [512,512]
  float* out1 = (float*)d_out;
  float* out2 = out1 + (size_t)NB*TT*HH;
  short* projb = (short*)out2;                   // bf16 proj scratch inside copy-2 region

  const size_t MSZ = (size_t)HH*HH;
  short* mats  = (short*)d_ws;                   // 22 slots bf16
  short* matsT = mats + 22*MSZ;
  short* Wihb  = matsT + 22*MSZ;                 // [512,256] bf16
  float* Y0 = (float*)(Wihb + (size_t)HH*II);
  float* Y1 = Y0 + (size_t)NCH*NB*HH;

  auto M = [&](int i){ return mats  + (size_t)i*MSZ; };
  auto T = [&](int i){ return matsT + (size_t)i*MSZ; };

  k_init_p1<<<dim3(8,8), 256, 0, stream>>>(Whh, M(0), T(0));
  k_cvt<<<dim3(64), 256, 0, stream>>>(Wih, Wihb, HH*II);

  ProdArgs pa;
  pa.A[0]=M(0); pa.Bt[0]=T(0); pa.C[0]=M(1); pa.Ct[0]=T(1);        // W^2
  k_prod<<<dim3(8,4,1), 256, 0, stream>>>(pa);
  pa.A[0]=M(1); pa.Bt[0]=T(0); pa.C[0]=M(2); pa.Ct[0]=T(2);        // W^3
  pa.A[1]=M(1); pa.Bt[1]=T(1); pa.C[1]=M(3); pa.Ct[1]=T(3);        // W^4
  k_prod<<<dim3(8,4,2), 256, 0, stream>>>(pa);
  for(int r = 1; r <= 4; ++r){ pa.A[r-1]=M(3); pa.Bt[r-1]=T(r-1); pa.C[r-1]=M(3+r); pa.Ct[r-1]=T(3+r); }
  k_prod<<<dim3(8,4,4), 256, 0, stream>>>(pa);                     // W^5..W^8
  for(int r = 1; r <= 8; ++r){ pa.A[r-1]=M(7); pa.Bt[r-1]=T(r-1); pa.C[r-1]=M(7+r); pa.Ct[r-1]=T(7+r); }
  k_prod<<<dim3(8,4,8), 256, 0, stream>>>(pa);                     // W^9..W^16
  int src = 15;
  for(int i = 16; i <= 21; ++i){                                   // W^32..W^1024
    pa.A[0]=M(src); pa.Bt[0]=T(src); pa.C[0]=M(i); pa.Ct[0]=T(i);
    k_prod<<<dim3(8,4,1), 256, 0, stream>>>(pa);
    src = i;
  }

  k_proj<<<dim3(1024,4), 256, 0, stream>>>(x, Wihb, bih, initial, projb, Y0);
  k_scan<<<dim3(NCH), 512, 0, stream>>>(projb, M(0), out1, Y0);

  struct { float* in; float* out; int slot; int s; } lv[7] = {
    {Y0,Y1,15, 1},{Y1,Y0,16, 2},{Y0,Y1,17, 4},{Y1,Y0,18, 8},
    {Y0,Y1,19,16},{Y1,Y0,20,32},{Y0,Y1,21,64}
  };
  for(int l = 0; l < 7; ++l)
    k_ks<<<dim3(NCH), 256, 0, stream>>>(lv[l].in, lv[l].out, M(lv[l].slot), lv[l].s);

  k_fix<<<dim3(64,4,LCH+1), 256, 0, stream>>>(Y1, mats, out1, out2);
}